// Round 1
// baseline (1227.647 us; speedup 1.0000x reference)
//
#include <hip/hip_runtime.h>
#include <cstdint>
#include <cstddef>

#define T_ 32
#define N_ 2048
#define POS_ 256
#define H_ 64
#define E_ 128
#define S_ 16
#define R_ 4

__device__ __forceinline__ float wave_sum64(float v) {
  #pragma unroll
  for (int off = 32; off > 0; off >>= 1) v += __shfl_xor(v, off, 64);
  return v;
}

// out[n][h] = sum_k pe[n][k] * W[k][h] + b[h]   (k < 256)
__global__ __launch_bounds__(256) void k_posproj(
    const float* __restrict__ pe, const float* __restrict__ W,
    const float* __restrict__ b, float* __restrict__ out) {
  int tid = threadIdx.x;
  int n = blockIdx.x * 4 + (tid >> 6);
  int h = tid & 63;
  const float* per = pe + (size_t)n * POS_;
  float acc = b[h];
  for (int k = 0; k < POS_; ++k) acc += per[k] * W[k * H_ + h];
  out[(size_t)n * H_ + h] = acc;
}

// C[t] = G[t] (2048x2048) @ B[t] (2048x64); B batch stride 0 (shared) or N*H
__global__ __launch_bounds__(256) void k_gemm_graph(
    const float* __restrict__ G, const float* __restrict__ B,
    float* __restrict__ C, long long bStride) {
  __shared__ __align__(16) float AsT[64][68];  // [k][m], padded
  __shared__ __align__(16) float Bs[64][68];   // [k][h], padded
  int t = blockIdx.y;
  int rowBase = blockIdx.x * 64;
  const float* Gt = G + (size_t)t * N_ * N_ + (size_t)rowBase * N_;
  const float* Bt = B + (size_t)t * bStride;
  int tid = threadIdx.x;
  int tx = tid & 15, ty = tid >> 4;
  float acc[4][4] = {};
  for (int k0 = 0; k0 < N_; k0 += 64) {
    #pragma unroll
    for (int ch = 0; ch < 4; ++ch) {
      int li = tid * 4 + ch * 1024;
      int r = li >> 6, c = li & 63;
      float4 v = *reinterpret_cast<const float4*>(Gt + (size_t)r * N_ + k0 + c);
      AsT[c + 0][r] = v.x; AsT[c + 1][r] = v.y;
      AsT[c + 2][r] = v.z; AsT[c + 3][r] = v.w;
    }
    #pragma unroll
    for (int ch = 0; ch < 4; ++ch) {
      int li = tid * 4 + ch * 1024;
      int k = li >> 6, h = li & 63;
      float4 v = *reinterpret_cast<const float4*>(Bt + (size_t)(k0 + k) * H_ + h);
      *reinterpret_cast<float4*>(&Bs[k][h]) = v;
    }
    __syncthreads();
    #pragma unroll
    for (int kk = 0; kk < 64; ++kk) {
      float4 a = *reinterpret_cast<const float4*>(&AsT[kk][ty * 4]);
      float4 bb = *reinterpret_cast<const float4*>(&Bs[kk][tx * 4]);
      float av[4] = {a.x, a.y, a.z, a.w};
      float bv[4] = {bb.x, bb.y, bb.z, bb.w};
      #pragma unroll
      for (int i = 0; i < 4; ++i)
        #pragma unroll
        for (int j = 0; j < 4; ++j) acc[i][j] += av[i] * bv[j];
    }
    __syncthreads();
  }
  float* Ct = C + (size_t)t * N_ * H_ + (size_t)rowBase * H_;
  #pragma unroll
  for (int i = 0; i < 4; ++i) {
    float4 v = make_float4(acc[i][0], acc[i][1], acc[i][2], acc[i][3]);
    *reinterpret_cast<float4*>(Ct + (size_t)(ty * 4 + i) * H_ + tx * 4) = v;
  }
}

// x1[pos] = LN(relu(pe_ctr[n] + agg[pos] @ W2)) ; W2 = g1_upd_w rows 256..319
__global__ __launch_bounds__(256) void k_g1_update(
    const float* __restrict__ agg, const float* __restrict__ pe_ctr,
    const float* __restrict__ W2, const float* __restrict__ lng,
    const float* __restrict__ lnb, float* __restrict__ x1) {
  __shared__ float Ws[64][65];
  __shared__ float as[4][64];
  int tid = threadIdx.x;
  for (int i = tid; i < 64 * 64; i += 256) Ws[i >> 6][i & 63] = W2[i];
  long long pos0 = (long long)blockIdx.x * 4;
  as[tid >> 6][tid & 63] = agg[pos0 * 64 + tid];
  __syncthreads();
  int p = tid >> 6, h = tid & 63;
  long long pos = pos0 + p;
  int n = (int)(pos % N_);
  float v = pe_ctr[(size_t)n * H_ + h];
  for (int k = 0; k < 64; ++k) v += as[p][k] * Ws[k][h];
  v = fmaxf(v, 0.f);
  float m = wave_sum64(v) * (1.f / 64.f);
  float d = v - m;
  float var = wave_sum64(d * d) * (1.f / 64.f);
  x1[pos * 64 + h] = d * rsqrtf(var + 1e-5f) * lng[h] + lnb[h];
}

// out[pos] = in[pos] @ W (64x64) + b
__global__ __launch_bounds__(256) void k_rowgemm64(
    const float* __restrict__ in, const float* __restrict__ W,
    const float* __restrict__ b, float* __restrict__ out) {
  __shared__ float Ws[64][65];
  __shared__ float as[4][64];
  int tid = threadIdx.x;
  for (int i = tid; i < 64 * 64; i += 256) Ws[i >> 6][i & 63] = W[i];
  long long pos0 = (long long)blockIdx.x * 4;
  as[tid >> 6][tid & 63] = in[pos0 * 64 + tid];
  __syncthreads();
  int p = tid >> 6, h = tid & 63;
  float v = b[h];
  for (int k = 0; k < 64; ++k) v += as[p][k] * Ws[k][h];
  out[(pos0 + p) * 64 + h] = v;
}

// x2[pos] = LN(relu(x1[pos]@W[0:64] + agg2[pos]@W[64:128] + b))
__global__ __launch_bounds__(256) void k_g2_update(
    const float* __restrict__ x1, const float* __restrict__ agg2,
    const float* __restrict__ W, const float* __restrict__ b,
    const float* __restrict__ lng, const float* __restrict__ lnb,
    float* __restrict__ x2) {
  __shared__ float Ws[128][65];
  __shared__ float as[4][64], bs[4][64];
  int tid = threadIdx.x;
  for (int i = tid; i < 128 * 64; i += 256) Ws[i >> 6][i & 63] = W[i];
  long long pos0 = (long long)blockIdx.x * 4;
  as[tid >> 6][tid & 63] = x1[pos0 * 64 + tid];
  bs[tid >> 6][tid & 63] = agg2[pos0 * 64 + tid];
  __syncthreads();
  int p = tid >> 6, h = tid & 63;
  float v = b[h];
  for (int k = 0; k < 64; ++k)
    v += as[p][k] * Ws[k][h] + bs[p][k] * Ws[64 + k][h];
  v = fmaxf(v, 0.f);
  float m = wave_sum64(v) * (1.f / 64.f);
  float d = v - m;
  float var = wave_sum64(d * d) * (1.f / 64.f);
  x2[(pos0 + p) * 64 + h] = d * rsqrtf(var + 1e-5f) * lng[h] + lnb[h];
}

// per (t,n): xn = LN(x2[t,n]); z = xn@in_w + in_b (256); xp=silu(z[:128]); sg=silu(z[128:])
__global__ __launch_bounds__(256) void k_mamba_in(
    const float* __restrict__ x2, const float* __restrict__ lng,
    const float* __restrict__ lnb, const float* __restrict__ in_w,
    const float* __restrict__ in_b, float* __restrict__ xp,
    float* __restrict__ sg) {
  __shared__ float xs[64];
  int bid = blockIdx.x;
  int t = bid >> 11, n = bid & 2047;
  int tid = threadIdx.x;
  if (tid < 64) {
    float v = x2[((size_t)t * N_ + n) * 64 + tid];
    float m = wave_sum64(v) * (1.f / 64.f);
    float d = v - m;
    float var = wave_sum64(d * d) * (1.f / 64.f);
    xs[tid] = d * rsqrtf(var + 1e-5f) * lng[tid] + lnb[tid];
  }
  __syncthreads();
  int j = tid;
  float z = in_b[j];
  for (int k = 0; k < 64; ++k) z += xs[k] * in_w[k * 256 + j];
  float sz = z / (1.f + __expf(-z));
  size_t base = ((size_t)n * T_ + t) * E_;
  if (j < 128) xp[base + j] = sz;
  else sg[base + (j - 128)] = sz;
}

// per (n,t): delta = softplus((xp@dp_w+dp_b)@dt_w+dt_b); Bm = xp@B_w+B_b; Cm = xp@C_w+C_b
__global__ __launch_bounds__(128) void k_mamba_dbc(
    const float* __restrict__ xp, const float* __restrict__ dp_w,
    const float* __restrict__ dp_b, const float* __restrict__ dt_w,
    const float* __restrict__ dt_b, const float* __restrict__ B_w,
    const float* __restrict__ B_b, const float* __restrict__ C_w,
    const float* __restrict__ C_b, float* __restrict__ delta,
    float* __restrict__ Bm, float* __restrict__ Cm) {
  __shared__ float xs[128];
  __shared__ float rs[4];
  size_t base = (size_t)blockIdx.x * E_;
  int tid = threadIdx.x;
  xs[tid] = xp[base + tid];
  __syncthreads();
  if (tid < 4) {
    float r = dp_b[tid];
    for (int e = 0; e < 128; ++e) r += xs[e] * dp_w[e * 4 + tid];
    rs[tid] = r;
  }
  if (tid >= 64 && tid < 80) {
    int s = tid - 64;
    float v = B_b[s];
    for (int e = 0; e < 128; ++e) v += xs[e] * B_w[e * 16 + s];
    Bm[(size_t)blockIdx.x * S_ + s] = v;
  }
  if (tid >= 80 && tid < 96) {
    int s = tid - 80;
    float v = C_b[s];
    for (int e = 0; e < 128; ++e) v += xs[e] * C_w[e * 16 + s];
    Cm[(size_t)blockIdx.x * S_ + s] = v;
  }
  __syncthreads();
  float d = dt_b[tid];
  #pragma unroll
  for (int q = 0; q < 4; ++q) d += rs[q] * dt_w[q * 128 + tid];
  delta[base + tid] = (d > 20.f) ? d : log1pf(__expf(d));
}

// one block per node: sequential scan over T, fused output projection + residual
__global__ __launch_bounds__(128) void k_scan(
    const float* __restrict__ xp, const float* __restrict__ sg,
    const float* __restrict__ delta, const float* __restrict__ Bm,
    const float* __restrict__ Cm, const float* __restrict__ A_log,
    const float* __restrict__ Dp, const float* __restrict__ out_w,
    const float* __restrict__ out_b, const float* __restrict__ x2,
    float* __restrict__ out) {
  __shared__ float ow[128][64];
  __shared__ float Bs[16], Cs[16];
  __shared__ float ys[128];
  __shared__ float ps[2][64];
  int n = blockIdx.x;
  int e = threadIdx.x;
  for (int i = e; i < 128 * 64; i += 128) ow[i >> 6][i & 63] = out_w[i];
  float Arow[16];
  #pragma unroll
  for (int s = 0; s < S_; ++s) Arow[s] = -__expf(A_log[e * S_ + s]);
  float dpv = Dp[e];
  float h[16];
  #pragma unroll
  for (int s = 0; s < 16; ++s) h[s] = 0.f;
  int hh = e & 63, half = e >> 6;
  for (int t = 0; t < T_; ++t) {
    size_t base = ((size_t)n * T_ + t) * E_;
    if (e < 16) Bs[e] = Bm[((size_t)n * T_ + t) * S_ + e];
    else if (e < 32) Cs[e - 16] = Cm[((size_t)n * T_ + t) * S_ + (e - 16)];
    float dt = delta[base + e];
    float xv = xp[base + e];
    float sgv = sg[base + e];
    __syncthreads();
    float y = 0.f;
    float dx = dt * xv;
    #pragma unroll
    for (int s = 0; s < 16; ++s) {
      h[s] = __expf(dt * Arow[s]) * h[s] + dx * Bs[s];
      y += Cs[s] * h[s];
    }
    y = (y + xv * dpv) * sgv;
    ys[e] = y;
    __syncthreads();
    float partial = 0.f;
    #pragma unroll
    for (int k = 0; k < 64; ++k)
      partial += ys[half * 64 + k] * ow[half * 64 + k][hh];
    ps[half][hh] = partial;
    __syncthreads();
    if (e < 64) {
      out[((size_t)t * N_ + n) * 64 + e] =
          ps[0][e] + ps[1][e] + out_b[e] + x2[((size_t)t * N_ + n) * 64 + e];
    }
  }
}

extern "C" void kernel_launch(void* const* d_in, const int* in_sizes, int n_in,
                              void* d_out, int out_size, void* d_ws, size_t ws_size,
                              hipStream_t stream) {
  const float* G        = (const float*)d_in[0];
  const float* pe       = (const float*)d_in[1];
  const float* g1_msg_w = (const float*)d_in[2];
  const float* g1_msg_b = (const float*)d_in[3];
  const float* g1_upd_w = (const float*)d_in[4];
  const float* g1_upd_b = (const float*)d_in[5];
  const float* g1_ln_g  = (const float*)d_in[6];
  const float* g1_ln_b  = (const float*)d_in[7];
  const float* g2_msg_w = (const float*)d_in[8];
  const float* g2_msg_b = (const float*)d_in[9];
  const float* g2_upd_w = (const float*)d_in[10];
  const float* g2_upd_b = (const float*)d_in[11];
  const float* g2_ln_g  = (const float*)d_in[12];
  const float* g2_ln_b  = (const float*)d_in[13];
  const float* m_ln_g   = (const float*)d_in[14];
  const float* m_ln_b   = (const float*)d_in[15];
  const float* in_w     = (const float*)d_in[16];
  const float* in_b     = (const float*)d_in[17];
  const float* dp_w     = (const float*)d_in[18];
  const float* dp_b     = (const float*)d_in[19];
  const float* dt_w     = (const float*)d_in[20];
  const float* dt_b     = (const float*)d_in[21];
  const float* A_log    = (const float*)d_in[22];
  const float* Dp       = (const float*)d_in[23];
  const float* B_w      = (const float*)d_in[24];
  const float* B_b      = (const float*)d_in[25];
  const float* C_w      = (const float*)d_in[26];
  const float* C_b      = (const float*)d_in[27];
  const float* out_w    = (const float*)d_in[28];
  const float* out_b    = (const float*)d_in[29];

  float* ws = (float*)d_ws;
  float* msgs   = ws;                 // N*H
  float* pe_ctr = ws + 131072;        // N*H
  float* bufA   = ws + 262144;        // T*N*H  (agg, then agg2; later Bm/Cm)
  float* bufB   = ws + 4456448;       // x1      (later delta, spans bufB+bufC)
  float* bufC   = ws + 8650752;       // msgs2
  float* bufD   = ws + 12845056;      // x2 (residual, live till end)
  float* xp     = ws + 17039360;      // N*T*E
  float* sgb    = ws + 25427968;      // N*T*E
  float* delta  = bufB;               // reuse: x1+msgs2 dead by now (8388608 floats)
  float* Bm     = bufA;               // reuse: agg2 dead (1048576 floats)
  float* Cm     = bufA + 1048576;     // (1048576 floats)

  k_posproj<<<N_ / 4, 256, 0, stream>>>(pe, g1_msg_w, g1_msg_b, msgs);
  k_posproj<<<N_ / 4, 256, 0, stream>>>(pe, g1_upd_w, g1_upd_b, pe_ctr);
  k_gemm_graph<<<dim3(N_ / 64, T_), 256, 0, stream>>>(G, msgs, bufA, 0LL);
  k_g1_update<<<(T_ * N_) / 4, 256, 0, stream>>>(bufA, pe_ctr, g1_upd_w + 256 * 64,
                                                 g1_ln_g, g1_ln_b, bufB);
  k_rowgemm64<<<(T_ * N_) / 4, 256, 0, stream>>>(bufB, g2_msg_w, g2_msg_b, bufC);
  k_gemm_graph<<<dim3(N_ / 64, T_), 256, 0, stream>>>(G, bufC, bufA, (long long)N_ * H_);
  k_g2_update<<<(T_ * N_) / 4, 256, 0, stream>>>(bufB, bufA, g2_upd_w, g2_upd_b,
                                                 g2_ln_g, g2_ln_b, bufD);
  k_mamba_in<<<T_ * N_, 256, 0, stream>>>(bufD, m_ln_g, m_ln_b, in_w, in_b, xp, sgb);
  k_mamba_dbc<<<N_ * T_, 128, 0, stream>>>(xp, dp_w, dp_b, dt_w, dt_b,
                                           B_w, B_b, C_w, C_b, delta, Bm, Cm);
  k_scan<<<N_, 128, 0, stream>>>(xp, sgb, delta, Bm, Cm, A_log, Dp,
                                 out_w, out_b, bufD, (float*)d_out);
}